// Round 14
// baseline (553.526 us; speedup 1.0000x reference)
//
#include <hip/hip_runtime.h>

#define H 768
#define FF 3072
#define NH 12
#define DH 64
#define SEQ 2048
#define MTOK 4096

typedef __attribute__((ext_vector_type(8))) short short8;
typedef __attribute__((ext_vector_type(4))) float f32x4;
typedef __attribute__((ext_vector_type(2))) unsigned int uint2v;

// swizzled fragment layout for all GEMM operands (A [M,K] and B^T [N,K] alike):
//   tile(mt,kt) base = ((m>>4)*(K>>5) + (k>>5))*512   [shorts], 16x32 tile
//   in-tile off(r=m&15, c=k&31) = r*32 + (c ^ ((r&3)<<3))     <- T2 XOR swizzle
// each tile = 1KB contiguous -> staged to LDS linearly by gld16; GEMM ds_read
// applies the same XOR.

__device__ __forceinline__ f32x4 mfma16(short8 a, short8 b, f32x4 c) {
  return __builtin_amdgcn_mfma_f32_16x16x32_bf16(a, b, c, 0, 0, 0);
}

__device__ __forceinline__ unsigned short f2bf(float f) {
  union { float f; unsigned int u; } c; c.f = f;
  unsigned int u = c.u;
  u += 0x7fffu + ((u >> 16) & 1u);  // round-to-nearest-even
  return (unsigned short)(u >> 16);
}
__device__ __forceinline__ float bf2f(unsigned short s) {
  union { unsigned int u; float f; } c; c.u = ((unsigned int)s) << 16;
  return c.f;
}
__device__ __forceinline__ unsigned int pk2bf(float lo, float hi) {
  return (unsigned int)f2bf(lo) | ((unsigned int)f2bf(hi) << 16);
}
// truncating bf16 pair pack: one v_perm_b32
__device__ __forceinline__ unsigned int pktrunc(float lo, float hi) {
  union { float f; unsigned int u; } a, b; a.f = hi; b.f = lo;
  return __builtin_amdgcn_perm(a.u, b.u, 0x07060302u);
}

// async global->LDS, 16B per lane; LDS dest = wave-uniform base + lane*16
__device__ __forceinline__ void gld16(const unsigned short* g, unsigned short* l) {
  __builtin_amdgcn_global_load_lds(
      (const __attribute__((address_space(1))) void*)g,
      (__attribute__((address_space(3))) void*)l, 16, 0, 0);
}

// ---------------- fused: weight transposes (bid<6912) + LN1 (bid>=6912) ----------------
// transposes write swizzled fragment layout; LN writes nx likewise (K=768)
__global__ __launch_bounds__(256) void prep_kernel(
    const float* __restrict__ Wq, const float* __restrict__ Wk,
    const float* __restrict__ Wv, const float* __restrict__ Wo,
    const float* __restrict__ W1, const float* __restrict__ W2,
    unsigned short* __restrict__ WqkvT, unsigned short* __restrict__ WoT,
    unsigned short* __restrict__ W1T, unsigned short* __restrict__ W2T,
    const float* __restrict__ latent, const float* __restrict__ ln1_w,
    const float* __restrict__ ln1_b, unsigned short* __restrict__ nx) {
  int bid = blockIdx.x;
  int tid = threadIdx.x;
  if (bid >= 6912) {
    int row = bid - 6912;
    const float* xr = latent + (size_t)row * H;
    float v0 = xr[tid], v1 = xr[tid + 256], v2 = xr[tid + 512];
    float s = v0 + v1 + v2;
    float ss = v0 * v0 + v1 * v1 + v2 * v2;
#pragma unroll
    for (int off = 32; off > 0; off >>= 1) {
      s += __shfl_down(s, off);
      ss += __shfl_down(ss, off);
    }
    __shared__ float red[8];
    int wave = tid >> 6, lane = tid & 63;
    if (lane == 0) { red[wave] = s; red[4 + wave] = ss; }
    __syncthreads();
    s = red[0] + red[1] + red[2] + red[3];
    ss = red[4] + red[5] + red[6] + red[7];
    float mu = s * (1.0f / H);
    float var = ss * (1.0f / H) - mu * mu;
    float rs = rsqrtf(var + 1e-6f);
    // swizzled fragment write: K=768 -> 24 k-tiles per 16-row tile
    unsigned short* orow = nx + (size_t)(row >> 4) * (24 * 512) + (row & 15) * 32;
    int col = (tid & 31) ^ ((row & 3) << 3);
    int kb = (tid >> 5) * 512 + col;
    orow[kb]            = f2bf((v0 - mu) * rs * ln1_w[tid]       + ln1_b[tid]);
    orow[kb + 8 * 512]  = f2bf((v1 - mu) * rs * ln1_w[tid + 256] + ln1_b[tid + 256]);
    orow[kb + 16 * 512] = f2bf((v2 - mu) * rs * ln1_w[tid + 512] + ln1_b[tid + 512]);
    return;
  }
  const float* in; unsigned short* out; int K, N, t0;
  if (bid < 1728) {
    K = 768; N = 768;
    if (bid < 576)       { in = Wq; out = WqkvT;                       t0 = bid; }
    else if (bid < 1152) { in = Wk; out = WqkvT + (size_t)768 * 768;   t0 = bid - 576; }
    else                 { in = Wv; out = WqkvT + (size_t)1536 * 768;  t0 = bid - 1152; }
  } else if (bid < 2304) { in = Wo; out = WoT; K = 768;  N = 768;  t0 = bid - 1728; }
  else if (bid < 4608)   { in = W1; out = W1T; K = 768;  N = 3072; t0 = bid - 2304; }
  else                   { in = W2; out = W2T; K = 3072; N = 768;  t0 = bid - 4608; }

  __shared__ float tile[32][33];
  int nb = N >> 5;
  int n0 = (t0 % nb) << 5;
  int k0 = (t0 / nb) << 5;
  int tx = tid & 31, ty = tid >> 5;
#pragma unroll
  for (int yy = 0; yy < 4; ++yy)
    tile[ty + yy * 8][tx] = in[(size_t)(k0 + ty + yy * 8) * N + n0 + tx];
  __syncthreads();
  int KT5 = K >> 5;
#pragma unroll
  for (int yy = 0; yy < 4; ++yy) {
    int n = n0 + ty + yy * 8;
    out[(size_t)((n >> 4) * KT5 + (k0 >> 5)) * 512 + (n & 15) * 32
        + (tx ^ ((n & 3) << 3))]
        = f2bf(tile[tx][ty + yy * 8]);
  }
}

// ---------------- LayerNorm fp32 [rows][768] -> bf16 swizzled fragment layout ----------------
__global__ __launch_bounds__(256) void ln_kernel(const float* __restrict__ x,
                                                 const float* __restrict__ w,
                                                 const float* __restrict__ b,
                                                 unsigned short* __restrict__ out) {
  int row = blockIdx.x;
  int tid = threadIdx.x;
  const float* xr = x + (size_t)row * H;
  float v0 = xr[tid], v1 = xr[tid + 256], v2 = xr[tid + 512];
  float s = v0 + v1 + v2;
  float ss = v0 * v0 + v1 * v1 + v2 * v2;
#pragma unroll
  for (int off = 32; off > 0; off >>= 1) {
    s += __shfl_down(s, off);
    ss += __shfl_down(ss, off);
  }
  __shared__ float red[8];
  int wave = tid >> 6, lane = tid & 63;
  if (lane == 0) { red[wave] = s; red[4 + wave] = ss; }
  __syncthreads();
  s = red[0] + red[1] + red[2] + red[3];
  ss = red[4] + red[5] + red[6] + red[7];
  float mu = s * (1.0f / H);
  float var = ss * (1.0f / H) - mu * mu;
  float rs = rsqrtf(var + 1e-6f);
  unsigned short* orow = out + (size_t)(row >> 4) * (24 * 512) + (row & 15) * 32;
  int col = (tid & 31) ^ ((row & 3) << 3);
  int kb = (tid >> 5) * 512 + col;
  orow[kb]            = f2bf((v0 - mu) * rs * w[tid]       + b[tid]);
  orow[kb + 8 * 512]  = f2bf((v1 - mu) * rs * w[tid + 256] + b[tid + 256]);
  orow[kb + 16 * 512] = f2bf((v2 - mu) * rs * w[tid + 512] + b[tid + 512]);
}

// ---------------- GEMM 128x128, BK=64, LDS-staged from swizzled fragment layout ----------------
// staging = contiguous 1KB tile copies; ds_read applies the row XOR
// K' layout (per bh, per 32-key chunk c): shorts offset =
//   c*2048 + sub*1024 + dhh*512 + k16*32 + (dh&31)
// V' layout (per bh, per chunk c): c*2048 + dt*512 + (slot>>3)*128 + (d&15)*8 + (slot&7)
//   slot bits [k4 k2 k1 k3 k0] of key5 bits [k4 k3 k2 k1 k0]  (pi^-1 for permlane32_swap)
enum { MODE_QKV = 0, MODE_RESID = 1, MODE_GELU = 2 };

template <int MODE>
__global__ __launch_bounds__(256) void gemm128(
    const unsigned short* __restrict__ A,   // swz fragment layout, M rows, K cols
    const unsigned short* __restrict__ Bt,  // swz fragment layout, N rows, K cols
    int M, int N, int K,
    const float* __restrict__ bias0,
    const float* __restrict__ bias1,
    const float* __restrict__ bias2,
    unsigned short* __restrict__ out_q,
    unsigned short* __restrict__ out_k,    // K' layout
    unsigned short* __restrict__ out_vT,   // V' layout (permuted)
    unsigned short* __restrict__ out_bf)   // swz fragment layout [M, N-as-K]
{
  const int mb = M >> 7;
  int m0 = (blockIdx.x % mb) << 7;        // m-major: same n-strip stays adjacent
  int n0 = (blockIdx.x / mb) << 7;
  int tid = threadIdx.x;
  int wave = tid >> 6, lane = tid & 63;
  int quad = lane >> 4, l16 = lane & 15;
  int wm = (wave & 1) << 6;
  int wn = (wave >> 1) << 6;
  int KT = K >> 5;
  const size_t TS = (size_t)KT * 512;     // shorts per 16-row tile strip
  int swq = (quad ^ (l16 & 3)) << 3;      // swizzled in-tile column (shorts)

  __shared__ __align__(16) unsigned short As[2][128 * 32];
  __shared__ __align__(16) unsigned short Bs[2][128 * 32];

  f32x4 acc[4][4];
#pragma unroll
  for (int i = 0; i < 4; ++i)
#pragma unroll
    for (int j = 0; j < 4; ++j) acc[i][j] = (f32x4){0.f, 0.f, 0.f, 0.f};

  // wave stages rows [wave*32, wave*32+32) = mtiles 2*wave, 2*wave+1
  const unsigned short* gA = A + (size_t)((m0 >> 4) + wave * 2) * TS + lane * 8;
  const unsigned short* gB = Bt + (size_t)((n0 >> 4) + wave * 2) * TS + lane * 8;
  unsigned short* lA0 = &As[0][(wave * 32) * 32];
  unsigned short* lA1 = &As[0][(wave * 32 + 16) * 32];
  unsigned short* lB0 = &Bs[0][(wave * 32) * 32];
  unsigned short* lB1 = &Bs[0][(wave * 32 + 16) * 32];
  const int CH = 128 * 32;   // chunk stride in shorts

  for (int ktb = 0; ktb < KT; ktb += 2) {
#pragma unroll
    for (int kc = 0; kc < 2; ++kc) {
      gld16(gA + (size_t)(ktb + kc) * 512,      lA0 + kc * CH);
      gld16(gA + TS + (size_t)(ktb + kc) * 512, lA1 + kc * CH);
      gld16(gB + (size_t)(ktb + kc) * 512,      lB0 + kc * CH);
      gld16(gB + TS + (size_t)(ktb + kc) * 512, lB1 + kc * CH);
    }
    __syncthreads();
#pragma unroll
    for (int kc = 0; kc < 2; ++kc) {
      short8 af[4], bfr[4];
#pragma unroll
      for (int t = 0; t < 4; ++t)
        af[t] = *(const short8*)(&As[kc][(wm + t * 16 + l16) * 32 + swq]);
#pragma unroll
      for (int t = 0; t < 4; ++t)
        bfr[t] = *(const short8*)(&Bs[kc][(wn + t * 16 + l16) * 32 + swq]);
#pragma unroll
      for (int i = 0; i < 4; ++i)
#pragma unroll
        for (int j = 0; j < 4; ++j)
          acc[i][j] = mfma16(af[i], bfr[j], acc[i][j]);
    }
    __syncthreads();
  }

#pragma unroll
  for (int mt = 0; mt < 4; ++mt)
#pragma unroll
    for (int nt = 0; nt < 4; ++nt) {
      f32x4 c = acc[mt][nt];
      int m = m0 + wm + mt * 16 + quad * 4;
      int n = n0 + wn + nt * 16 + l16;
      if (MODE == MODE_QKV) {
        int bb = m >> 11, sIdx = m & 2047;
        if (n < 768) {
          float bs = bias0[n];
          int hh = n >> 6, d = n & 63;
          unsigned short* dst = out_q + (((size_t)(bb * NH + hh)) * SEQ + sIdx) * DH + d;
#pragma unroll
          for (int r = 0; r < 4; ++r) dst[r * DH] = f2bf(c[r] + bs);
        } else if (n < 1536) {
          int nn = n - 768;
          float bs = bias1[nn];
          int hh = nn >> 6, d = nn & 63;
          size_t base = (size_t)(bb * NH + hh) * (SEQ * DH)
                      + (size_t)(sIdx >> 5) * 2048 + ((sIdx >> 4) & 1) * 1024
                      + (d >> 5) * 512 + (sIdx & 15) * 32 + (d & 31);
#pragma unroll
          for (int r = 0; r < 4; ++r) out_k[base + r * 32] = f2bf(c[r] + bs);
        } else {
          int nn = n - 1536;
          float bs = bias2[nn];
          int hh = nn >> 6, d = nn & 63;
          // permuted V' slot: key5 bits [k4 k3 k2 k1 k0] -> slot [k4 k2 k1 k3 k0]
          int k5 = sIdx & 31;                    // k5&7 in {0,4}
          int sa = (k5 & 0x11) | ((k5 & 0x6) << 1) | ((k5 >> 2) & 0x2);
          size_t cb = (size_t)(bb * NH + hh) * (SEQ * DH)
                    + (size_t)(sIdx >> 5) * 2048 + (d >> 4) * 512
                    + (d & 15) * 8 + (size_t)(sa >> 3) * 128;
          *(unsigned int*)(out_vT + cb + (sa & 7))       = pk2bf(c[0] + bs, c[1] + bs);
          *(unsigned int*)(out_vT + cb + ((sa & 7) | 4)) = pk2bf(c[2] + bs, c[3] + bs);
        }
      } else {  // MODE_GELU: write swizzled fragment layout (out cols act as K next)
        float bs = bias0[n];
        int mtile = ((m0 + wm) >> 4) + mt;
        unsigned short* opb = out_bf + (size_t)(mtile * (N >> 5) + (n >> 5)) * 512
                              + quad * 4 * 32;
#pragma unroll
        for (int r = 0; r < 4; ++r) {
          float t = c[r] + bs;
          opb[r * 32 + ((n & 31) ^ ((r & 3) << 3))]
              = f2bf(0.5f * t * (1.0f + erff(t * 0.70710678118654752f)));
        }
      }
    }
}

// ---------------- GEMM 64x64, BK=128, LDS-staged from swizzled fragment layout ----------------
template <int TAG>
__global__ __launch_bounds__(256) void gemm64r(
    const unsigned short* __restrict__ A,   // swz fragment layout
    const unsigned short* __restrict__ Bt,  // swz fragment layout
    int M, int N, int K,
    const float* __restrict__ bias0,
    const float* __restrict__ resid,        // fp32 [M,N]
    float* __restrict__ out_f)              // fp32 [M,N]
{
  const int mb = M >> 6;
  int m0 = (blockIdx.x % mb) << 6;        // m-major ordering
  int n0 = (blockIdx.x / mb) << 6;
  int tid = threadIdx.x;
  int wave = tid >> 6, lane = tid & 63;
  int quad = lane >> 4, l16 = lane & 15;
  int wm = (wave & 1) << 5;
  int wn = (wave >> 1) << 5;
  int KT = K >> 5;
  const size_t TS = (size_t)KT * 512;
  int swq = (quad ^ (l16 & 3)) << 3;

  __shared__ __align__(16) unsigned short As[4][64 * 32];
  __shared__ __align__(16) unsigned short Bs[4][64 * 32];

  f32x4 acc[2][2];
#pragma unroll
  for (int i = 0; i < 2; ++i)
#pragma unroll
    for (int j = 0; j < 2; ++j) acc[i][j] = (f32x4){0.f, 0.f, 0.f, 0.f};

  // wave stages rows [wave*16, wave*16+16) = mtile wave
  const unsigned short* gA = A + (size_t)((m0 >> 4) + wave) * TS + lane * 8;
  const unsigned short* gB = Bt + (size_t)((n0 >> 4) + wave) * TS + lane * 8;
  unsigned short* lA = &As[0][wave * 512];
  unsigned short* lB = &Bs[0][wave * 512];
  const int CH = 64 * 32;   // chunk stride in shorts

  for (int ktb = 0; ktb < KT; ktb += 4) {
#pragma unroll
    for (int kc = 0; kc < 4; ++kc) {
      gld16(gA + (size_t)(ktb + kc) * 512, lA + kc * CH);
      gld16(gB + (size_t)(ktb + kc) * 512, lB + kc * CH);
    }
    __syncthreads();
#pragma unroll
    for (int kc = 0; kc < 4; ++kc) {
      short8 af[2], bfr[2];
#pragma unroll
      for (int t = 0; t < 2; ++t)
        af[t] = *(const short8*)(&As[kc][(wm + t * 16 + l16) * 32 + swq]);
#pragma unroll
      for (int t = 0; t < 2; ++t)
        bfr[t] = *(const short8*)(&Bs[kc][(wn + t * 16 + l16) * 32 + swq]);
#pragma unroll
      for (int i = 0; i < 2; ++i)
#pragma unroll
        for (int j = 0; j < 2; ++j)
          acc[i][j] = mfma16(af[i], bfr[j], acc[i][j]);
    }
    __syncthreads();
  }

#pragma unroll
  for (int mt = 0; mt < 2; ++mt)
#pragma unroll
    for (int nt = 0; nt < 2; ++nt) {
      f32x4 c = acc[mt][nt];
      int m = m0 + wm + mt * 16 + quad * 4;
      int n = n0 + wn + nt * 16 + l16;
      float bs = bias0[n];
      const float* rp = resid + (size_t)m * N + n;
      float* op = out_f + (size_t)m * N + n;
#pragma unroll
      for (int r = 0; r < 4; ++r) op[(size_t)r * N] = rp[(size_t)r * N] + c[r] + bs;
    }
}

// ---------------- flash attention v14: 8 waves/block, 256 keys/wave ----------------
// doubles resident wave parallelism (latency-bound regime); per-wave chain halves.
// epilogue: 8 partials; each wave reduces one (t,dt) combo.
__global__ __launch_bounds__(512, 8) void flash_attn_kernel(
    const unsigned short* __restrict__ q,   // [B,NH,S,DH]
    const unsigned short* __restrict__ k,   // K' layout
    const unsigned short* __restrict__ vT,  // V' layout (permuted)
    unsigned short* __restrict__ ctx)       // swz fragment layout [MTOK, 768]
{
  const float CEXP = 0.18033688011112042f;  // (1/8) * log2(e)
  int bh = blockIdx.x % 24;
  int qblk = blockIdx.x / 24;
  int b = bh / NH, h = bh % NH;
  int tid = threadIdx.x;
  int wave = tid >> 6, lane = tid & 63;
  int quad = lane >> 4, l16 = lane & 15;
  int qbase = qblk << 5;

  const unsigned short* qp = q + ((size_t)bh * SEQ + qbase) * DH;
  const unsigned short* kbh = k + (size_t)bh * (SEQ * DH);
  const unsigned short* vbh = vT + (size_t)bh * (SEQ * DH);

  short8 qf00 = *(const short8*)(qp + l16 * DH + quad * 8);
  short8 qf01 = *(const short8*)(qp + l16 * DH + 32 + quad * 8);
  short8 qf10 = *(const short8*)(qp + (16 + l16) * DH + quad * 8);
  short8 qf11 = *(const short8*)(qp + (16 + l16) * DH + 32 + quad * 8);

  // all-ones bf16 fragment (1.0 = 0x3F80)
  const short ONE = (short)0x3F80;
  short8 ones = (short8){ONE, ONE, ONE, ONE, ONE, ONE, ONE, ONE};

  f32x4 oacc[2][4];
  f32x4 lacc[2];
#pragma unroll
  for (int t = 0; t < 2; ++t) {
    lacc[t] = (f32x4){0.f, 0.f, 0.f, 0.f};
#pragma unroll
    for (int dt = 0; dt < 4; ++dt) oacc[t][dt] = (f32x4){0.f, 0.f, 0.f, 0.f};
  }

  int klin = (l16 * 4 + quad) * 8;
  int vlin = (quad * 16 + l16) * 8;

  int keylo = wave << 8;                      // 256 keys per wave
  for (int key0 = keylo; key0 < keylo + 256; key0 += 32) {
    int cbase = (key0 >> 5) * 2048;
    short8 ka0 = *(const short8*)(kbh + cbase + klin);
    short8 ka1 = *(const short8*)(kbh + cbase + 512 + klin);
    short8 kb0 = *(const short8*)(kbh + cbase + 1024 + klin);
    short8 kb1 = *(const short8*)(kbh + cbase + 1536 + klin);
    short8 vf0 = *(const short8*)(vbh + cbase + 0 * 512 + vlin);
    short8 vf1 = *(const short8*)(vbh + cbase + 1 * 512 + vlin);
    short8 vf2 = *(const short8*)(vbh + cbase + 2 * 512 + vlin);
    short8 vf3 = *(const short8*)(vbh + cbase + 3 * 512 + vlin);

#pragma unroll
    for (int t = 0; t < 2; ++t) {
      short8 q0 = t ? qf10 : qf00;
      short8 q1 = t ? qf11 : qf01;
      f32x4 s0 = (f32x4){0.f, 0.f, 0.f, 0.f};
      f32x4 s1 = (f32x4){0.f, 0.f, 0.f, 0.f};
      s0 = mfma16(ka0, q0, s0);
      s0 = mfma16(ka1, q1, s0);
      s1 = mfma16(kb0, q0, s1);
      s1 = mfma16(kb1, q1, s1);

      f32x4 p0, p1;
#pragma unroll
      for (int r = 0; r < 4; ++r) {
        p0[r] = __builtin_amdgcn_exp2f(s0[r] * CEXP);
        p1[r] = __builtin_amdgcn_exp2f(s1[r] * CEXP);
      }

      unsigned int d00 = pktrunc(p0[0], p0[1]);
      unsigned int d01 = pktrunc(p0[2], p0[3]);
      unsigned int d10 = pktrunc(p1[0], p1[1]);
      unsigned int d11 = pktrunc(p1[2], p1[3]);

      uint2v rA = __builtin_amdgcn_permlane32_swap(d00, d10, false, false);
      uint2v rB = __builtin_amdgcn_permlane32_swap(d01, d11, false, false);
      union { short8 s; unsigned int i[4]; } pf;
      pf.i[0] = rA[0];
      pf.i[1] = rA[1];
      pf.i[2] = rB[0];
      pf.i[3] = rB[1];

      oacc[t][0] = mfma16(vf0, pf.s, oacc[t][0]);
      oacc[t][1] = mfma16(vf1, pf.s, oacc[t][1]);
      oacc[t][2] = mfma16(vf2, pf.s, oacc[t][2]);
      oacc[t][3] = mfma16(vf3, pf.s, oacc[t][3]);
      lacc[t]    = mfma16(ones, pf.s, lacc[t]);   // L row-sum on matrix pipe
    }
  }

  __shared__ float lbuf[8][2][16];
  __shared__ uint2 obuf[8][2][4][64];

  // every accumulator row of lacc holds L for q=l16; take slot 0 from quad 0
  if (lane < 16) {
    lbuf[wave][0][lane] = lacc[0][0];
    lbuf[wave][1][lane] = lacc[1][0];
  }
#pragma unroll
  for (int t = 0; t < 2; ++t)
#pragma unroll
    for (int dt = 0; dt < 4; ++dt) {
      uint2 pk;
      pk.x = pk2bf(oacc[t][dt][0], oacc[t][dt][1]);
      pk.y = pk2bf(oacc[t][dt][2], oacc[t][dt][3]);
      obuf[wave][t][dt][lane] = pk;
    }
  __syncthreads();

  {
    int t = wave >> 2, dt = wave & 3;     // each wave reduces one (t,dt) combo
    f32x4 sum = (f32x4){0.f, 0.f, 0.f, 0.f};
#pragma unroll
    for (int w = 0; w < 8; ++w) {
      uint2 pk = obuf[w][t][dt][lane];
      sum[0] += bf2f((unsigned short)(pk.x & 0xffff));
      sum[1] += bf2f((unsigned short)(pk.x >> 16));
      sum[2] += bf2f((unsigned short)(pk.y & 0xffff));
      sum[3] += bf2f((unsigned short)(pk.y >> 16));
    }
    float lstar = 0.f;
#pragma unroll
    for (int w = 0; w < 8; ++w) lstar += lbuf[w][t][l16];
    float rinv = 1.0f / lstar;
    uint2 res;
    res.x = pk2bf(sum[0] * rinv, sum[1] * rinv);
    res.y = pk2bf(sum[2] * rinv, sum[3] * rinv);
    // swizzled fragment write: row r=l16, col c = (dt&1)*16 + quad*4, XOR bits 3-4
    int colsw = (((dt & 1) * 16 + quad * 4)) ^ ((l16 & 3) << 3);
    unsigned short* crow = ctx
        + ((size_t)((b * SEQ + qbase + t * 16) >> 4) * 24 + h * 2 + (dt >> 1)) * 512
        + l16 * 32 + colsw;
    *(uint2*)crow = res;
  }
}

// ---------------- launch ----------------
extern "C" void kernel_launch(void* const* d_in, const int* in_sizes, int n_in,
                              void* d_out, int out_size, void* d_ws, size_t ws_size,
                              hipStream_t stream) {
  const float* latent = (const float*)d_in[0];
  const float* ln1_w = (const float*)d_in[1];
  const float* ln1_b = (const float*)d_in[2];
  const float* Wq = (const float*)d_in[3];
  const float* bq = (const float*)d_in[4];
  const float* Wk = (const float*)d_in[5];
  const float* bk = (const float*)d_in[6];
  const float* Wv = (const float*)d_in[7];
  const float* bv = (const float*)d_in[8];
  const float* Wo = (const float*)d_in[9];
  const float* bo = (const float*)d_in[10];
  const float* ln2_w = (const float*)d_in[11];
  const float* ln2_b = (const float*)d_in[12];
  const float* W1 = (const float*)d_in[13];
  const float* b1 = (const float*)d_in[14];
  const float* W2 = (const float*)d_in[15];
  const float* b2 = (const float*)d_in[16];
  float* out = (float*)d_out;

  char* ws = (char*)d_ws;
  unsigned short* WqkvT = (unsigned short*)ws; ws += (size_t)2304 * 768 * 2;
  unsigned short* WoT   = (unsigned short*)ws; ws += (size_t)768 * 768 * 2;
  unsigned short* W1T   = (unsigned short*)ws; ws += (size_t)3072 * 768 * 2;
  unsigned short* W2T   = (unsigned short*)ws; ws += (size_t)768 * 3072 * 2;
  unsigned short* nx    = (unsigned short*)ws; ws += (size_t)MTOK * H * 2;
  unsigned short* nx2   = (unsigned short*)ws; ws += (size_t)MTOK * H * 2;
  unsigned short* qb    = (unsigned short*)ws; ws += (size_t)MTOK * H * 2;
  unsigned short* kb    = (unsigned short*)ws; ws += (size_t)MTOK * H * 2;
  unsigned short* vTb   = (unsigned short*)ws; ws += (size_t)MTOK * H * 2;
  unsigned short* ctx   = (unsigned short*)ws; ws += (size_t)MTOK * H * 2;
  unsigned short* hbuf  = (unsigned short*)ws; ws += (size_t)MTOK * FF * 2;
  float* x1             = (float*)ws;          ws += (size_t)MTOK * H * 4;

  // weight transposes (swz fragment layout) + LN1 (swz fragment layout), one launch
  prep_kernel<<<6912 + MTOK, 256, 0, stream>>>(
      Wq, Wk, Wv, Wo, W1, W2, WqkvT, WoT, W1T, W2T,
      latent, ln1_w, ln1_b, nx);

  // QKV projection (fused, N=2304), staged BK=64; K/V written in K'/V' layouts
  gemm128<MODE_QKV><<<32 * 18, 256, 0, stream>>>(
      nx, WqkvT, MTOK, 2304, 768, bq, bk, bv,
      qb, kb, vTb, nullptr);

  // attention (flash v14, 8 waves/block; ctx written in swz fragment layout)
  flash_attn_kernel<<<24 * 64, 512, 0, stream>>>(qb, kb, vTb, ctx);

  // output projection + residual -> x1 (fp32), staged BK=128
  gemm64r<0><<<64 * 12, 256, 0, stream>>>(
      ctx, WoT, MTOK, 768, 768, bo, latent, x1);

  // LN2 (swz fragment layout out)
  ln_kernel<<<MTOK, 256, 0, stream>>>(x1, ln2_w, ln2_b, nx2);

  // FFN up + GELU -> hbuf (swz fragment layout, K-dim 3072), staged BK=64
  gemm128<MODE_GELU><<<32 * 24, 256, 0, stream>>>(
      nx2, W1T, MTOK, 3072, 768, b1, nullptr, nullptr,
      nullptr, nullptr, nullptr, hbuf);

  // FFN down + residual -> d_out (fp32), staged BK=128
  gemm64r<1><<<64 * 12, 256, 0, stream>>>(
      hbuf, W2T, MTOK, 768, 3072, b2, x1, out);
}

// Round 15
// 260.345 us; speedup vs baseline: 2.1261x; 2.1261x over previous
//
#include <hip/hip_runtime.h>

#define H 768
#define FF 3072
#define NH 12
#define DH 64
#define SEQ 2048
#define MTOK 4096

typedef __attribute__((ext_vector_type(8))) short short8;
typedef __attribute__((ext_vector_type(4))) float f32x4;
typedef __attribute__((ext_vector_type(2))) unsigned int uint2v;

// swizzled fragment layout for all GEMM operands (A [M,K] and B^T [N,K] alike):
//   tile(mt,kt) base = ((m>>4)*(K>>5) + (k>>5))*512   [shorts], 16x32 tile
//   in-tile off(r=m&15, c=k&31) = r*32 + (c ^ ((r&3)<<3))     <- T2 XOR swizzle
// each tile = 1KB contiguous -> staged to LDS linearly by gld16; GEMM ds_read
// applies the same XOR.

__device__ __forceinline__ f32x4 mfma16(short8 a, short8 b, f32x4 c) {
  return __builtin_amdgcn_mfma_f32_16x16x32_bf16(a, b, c, 0, 0, 0);
}

__device__ __forceinline__ unsigned short f2bf(float f) {
  union { float f; unsigned int u; } c; c.f = f;
  unsigned int u = c.u;
  u += 0x7fffu + ((u >> 16) & 1u);  // round-to-nearest-even
  return (unsigned short)(u >> 16);
}
__device__ __forceinline__ float bf2f(unsigned short s) {
  union { unsigned int u; float f; } c; c.u = ((unsigned int)s) << 16;
  return c.f;
}
__device__ __forceinline__ unsigned int pk2bf(float lo, float hi) {
  return (unsigned int)f2bf(lo) | ((unsigned int)f2bf(hi) << 16);
}
// truncating bf16 pair pack: one v_perm_b32
__device__ __forceinline__ unsigned int pktrunc(float lo, float hi) {
  union { float f; unsigned int u; } a, b; a.f = hi; b.f = lo;
  return __builtin_amdgcn_perm(a.u, b.u, 0x07060302u);
}

// async global->LDS, 16B per lane; LDS dest = wave-uniform base + lane*16
__device__ __forceinline__ void gld16(const unsigned short* g, unsigned short* l) {
  __builtin_amdgcn_global_load_lds(
      (const __attribute__((address_space(1))) void*)g,
      (__attribute__((address_space(3))) void*)l, 16, 0, 0);
}

// ---------------- fused: weight transposes (bid<6912) + LN1 (bid>=6912) ----------------
// transposes write swizzled fragment layout; LN writes nx likewise (K=768)
__global__ __launch_bounds__(256) void prep_kernel(
    const float* __restrict__ Wq, const float* __restrict__ Wk,
    const float* __restrict__ Wv, const float* __restrict__ Wo,
    const float* __restrict__ W1, const float* __restrict__ W2,
    unsigned short* __restrict__ WqkvT, unsigned short* __restrict__ WoT,
    unsigned short* __restrict__ W1T, unsigned short* __restrict__ W2T,
    const float* __restrict__ latent, const float* __restrict__ ln1_w,
    const float* __restrict__ ln1_b, unsigned short* __restrict__ nx) {
  int bid = blockIdx.x;
  int tid = threadIdx.x;
  if (bid >= 6912) {
    int row = bid - 6912;
    const float* xr = latent + (size_t)row * H;
    float v0 = xr[tid], v1 = xr[tid + 256], v2 = xr[tid + 512];
    float s = v0 + v1 + v2;
    float ss = v0 * v0 + v1 * v1 + v2 * v2;
#pragma unroll
    for (int off = 32; off > 0; off >>= 1) {
      s += __shfl_down(s, off);
      ss += __shfl_down(ss, off);
    }
    __shared__ float red[8];
    int wave = tid >> 6, lane = tid & 63;
    if (lane == 0) { red[wave] = s; red[4 + wave] = ss; }
    __syncthreads();
    s = red[0] + red[1] + red[2] + red[3];
    ss = red[4] + red[5] + red[6] + red[7];
    float mu = s * (1.0f / H);
    float var = ss * (1.0f / H) - mu * mu;
    float rs = rsqrtf(var + 1e-6f);
    // swizzled fragment write: K=768 -> 24 k-tiles per 16-row tile
    unsigned short* orow = nx + (size_t)(row >> 4) * (24 * 512) + (row & 15) * 32;
    int col = (tid & 31) ^ ((row & 3) << 3);
    int kb = (tid >> 5) * 512 + col;
    orow[kb]            = f2bf((v0 - mu) * rs * ln1_w[tid]       + ln1_b[tid]);
    orow[kb + 8 * 512]  = f2bf((v1 - mu) * rs * ln1_w[tid + 256] + ln1_b[tid + 256]);
    orow[kb + 16 * 512] = f2bf((v2 - mu) * rs * ln1_w[tid + 512] + ln1_b[tid + 512]);
    return;
  }
  const float* in; unsigned short* out; int K, N, t0;
  if (bid < 1728) {
    K = 768; N = 768;
    if (bid < 576)       { in = Wq; out = WqkvT;                       t0 = bid; }
    else if (bid < 1152) { in = Wk; out = WqkvT + (size_t)768 * 768;   t0 = bid - 576; }
    else                 { in = Wv; out = WqkvT + (size_t)1536 * 768;  t0 = bid - 1152; }
  } else if (bid < 2304) { in = Wo; out = WoT; K = 768;  N = 768;  t0 = bid - 1728; }
  else if (bid < 4608)   { in = W1; out = W1T; K = 768;  N = 3072; t0 = bid - 2304; }
  else                   { in = W2; out = W2T; K = 3072; N = 768;  t0 = bid - 4608; }

  __shared__ float tile[32][33];
  int nb = N >> 5;
  int n0 = (t0 % nb) << 5;
  int k0 = (t0 / nb) << 5;
  int tx = tid & 31, ty = tid >> 5;
#pragma unroll
  for (int yy = 0; yy < 4; ++yy)
    tile[ty + yy * 8][tx] = in[(size_t)(k0 + ty + yy * 8) * N + n0 + tx];
  __syncthreads();
  int KT5 = K >> 5;
#pragma unroll
  for (int yy = 0; yy < 4; ++yy) {
    int n = n0 + ty + yy * 8;
    out[(size_t)((n >> 4) * KT5 + (k0 >> 5)) * 512 + (n & 15) * 32
        + (tx ^ ((n & 3) << 3))]
        = f2bf(tile[tx][ty + yy * 8]);
  }
}

// ---------------- LayerNorm fp32 [rows][768] -> bf16 swizzled fragment layout ----------------
__global__ __launch_bounds__(256) void ln_kernel(const float* __restrict__ x,
                                                 const float* __restrict__ w,
                                                 const float* __restrict__ b,
                                                 unsigned short* __restrict__ out) {
  int row = blockIdx.x;
  int tid = threadIdx.x;
  const float* xr = x + (size_t)row * H;
  float v0 = xr[tid], v1 = xr[tid + 256], v2 = xr[tid + 512];
  float s = v0 + v1 + v2;
  float ss = v0 * v0 + v1 * v1 + v2 * v2;
#pragma unroll
  for (int off = 32; off > 0; off >>= 1) {
    s += __shfl_down(s, off);
    ss += __shfl_down(ss, off);
  }
  __shared__ float red[8];
  int wave = tid >> 6, lane = tid & 63;
  if (lane == 0) { red[wave] = s; red[4 + wave] = ss; }
  __syncthreads();
  s = red[0] + red[1] + red[2] + red[3];
  ss = red[4] + red[5] + red[6] + red[7];
  float mu = s * (1.0f / H);
  float var = ss * (1.0f / H) - mu * mu;
  float rs = rsqrtf(var + 1e-6f);
  unsigned short* orow = out + (size_t)(row >> 4) * (24 * 512) + (row & 15) * 32;
  int col = (tid & 31) ^ ((row & 3) << 3);
  int kb = (tid >> 5) * 512 + col;
  orow[kb]            = f2bf((v0 - mu) * rs * w[tid]       + b[tid]);
  orow[kb + 8 * 512]  = f2bf((v1 - mu) * rs * w[tid + 256] + b[tid + 256]);
  orow[kb + 16 * 512] = f2bf((v2 - mu) * rs * w[tid + 512] + b[tid + 512]);
}

// ---------------- GEMM 128x128, BK=64, LDS-staged from swizzled fragment layout ----------------
// staging = contiguous 1KB tile copies; ds_read applies the row XOR
// K' layout (per bh, per 32-key chunk c): shorts offset =
//   c*2048 + sub*1024 + dhh*512 + k16*32 + (dh&31)
// V' layout (per bh, per chunk c): c*2048 + dt*512 + (slot>>3)*128 + (d&15)*8 + (slot&7)
//   slot bits [k4 k2 k1 k3 k0] of key5 bits [k4 k3 k2 k1 k0]  (pi^-1 for permlane32_swap)
enum { MODE_QKV = 0, MODE_RESID = 1, MODE_GELU = 2 };

template <int MODE>
__global__ __launch_bounds__(256) void gemm128(
    const unsigned short* __restrict__ A,   // swz fragment layout, M rows, K cols
    const unsigned short* __restrict__ Bt,  // swz fragment layout, N rows, K cols
    int M, int N, int K,
    const float* __restrict__ bias0,
    const float* __restrict__ bias1,
    const float* __restrict__ bias2,
    unsigned short* __restrict__ out_q,
    unsigned short* __restrict__ out_k,    // K' layout
    unsigned short* __restrict__ out_vT,   // V' layout (permuted)
    unsigned short* __restrict__ out_bf)   // swz fragment layout [M, N-as-K]
{
  const int mb = M >> 7;
  int m0 = (blockIdx.x % mb) << 7;        // m-major: same n-strip stays adjacent
  int n0 = (blockIdx.x / mb) << 7;
  int tid = threadIdx.x;
  int wave = tid >> 6, lane = tid & 63;
  int quad = lane >> 4, l16 = lane & 15;
  int wm = (wave & 1) << 6;
  int wn = (wave >> 1) << 6;
  int KT = K >> 5;
  const size_t TS = (size_t)KT * 512;     // shorts per 16-row tile strip
  int swq = (quad ^ (l16 & 3)) << 3;      // swizzled in-tile column (shorts)

  __shared__ __align__(16) unsigned short As[2][128 * 32];
  __shared__ __align__(16) unsigned short Bs[2][128 * 32];

  f32x4 acc[4][4];
#pragma unroll
  for (int i = 0; i < 4; ++i)
#pragma unroll
    for (int j = 0; j < 4; ++j) acc[i][j] = (f32x4){0.f, 0.f, 0.f, 0.f};

  // wave stages rows [wave*32, wave*32+32) = mtiles 2*wave, 2*wave+1
  const unsigned short* gA = A + (size_t)((m0 >> 4) + wave * 2) * TS + lane * 8;
  const unsigned short* gB = Bt + (size_t)((n0 >> 4) + wave * 2) * TS + lane * 8;
  unsigned short* lA0 = &As[0][(wave * 32) * 32];
  unsigned short* lA1 = &As[0][(wave * 32 + 16) * 32];
  unsigned short* lB0 = &Bs[0][(wave * 32) * 32];
  unsigned short* lB1 = &Bs[0][(wave * 32 + 16) * 32];
  const int CH = 128 * 32;   // chunk stride in shorts

  for (int ktb = 0; ktb < KT; ktb += 2) {
#pragma unroll
    for (int kc = 0; kc < 2; ++kc) {
      gld16(gA + (size_t)(ktb + kc) * 512,      lA0 + kc * CH);
      gld16(gA + TS + (size_t)(ktb + kc) * 512, lA1 + kc * CH);
      gld16(gB + (size_t)(ktb + kc) * 512,      lB0 + kc * CH);
      gld16(gB + TS + (size_t)(ktb + kc) * 512, lB1 + kc * CH);
    }
    __syncthreads();
#pragma unroll
    for (int kc = 0; kc < 2; ++kc) {
      short8 af[4], bfr[4];
#pragma unroll
      for (int t = 0; t < 4; ++t)
        af[t] = *(const short8*)(&As[kc][(wm + t * 16 + l16) * 32 + swq]);
#pragma unroll
      for (int t = 0; t < 4; ++t)
        bfr[t] = *(const short8*)(&Bs[kc][(wn + t * 16 + l16) * 32 + swq]);
#pragma unroll
      for (int i = 0; i < 4; ++i)
#pragma unroll
        for (int j = 0; j < 4; ++j)
          acc[i][j] = mfma16(af[i], bfr[j], acc[i][j]);
    }
    __syncthreads();
  }

#pragma unroll
  for (int mt = 0; mt < 4; ++mt)
#pragma unroll
    for (int nt = 0; nt < 4; ++nt) {
      f32x4 c = acc[mt][nt];
      int m = m0 + wm + mt * 16 + quad * 4;
      int n = n0 + wn + nt * 16 + l16;
      if (MODE == MODE_QKV) {
        int bb = m >> 11, sIdx = m & 2047;
        if (n < 768) {
          float bs = bias0[n];
          int hh = n >> 6, d = n & 63;
          unsigned short* dst = out_q + (((size_t)(bb * NH + hh)) * SEQ + sIdx) * DH + d;
#pragma unroll
          for (int r = 0; r < 4; ++r) dst[r * DH] = f2bf(c[r] + bs);
        } else if (n < 1536) {
          int nn = n - 768;
          float bs = bias1[nn];
          int hh = nn >> 6, d = nn & 63;
          size_t base = (size_t)(bb * NH + hh) * (SEQ * DH)
                      + (size_t)(sIdx >> 5) * 2048 + ((sIdx >> 4) & 1) * 1024
                      + (d >> 5) * 512 + (sIdx & 15) * 32 + (d & 31);
#pragma unroll
          for (int r = 0; r < 4; ++r) out_k[base + r * 32] = f2bf(c[r] + bs);
        } else {
          int nn = n - 1536;
          float bs = bias2[nn];
          int hh = nn >> 6, d = nn & 63;
          // permuted V' slot: key5 bits [k4 k3 k2 k1 k0] -> slot [k4 k2 k1 k3 k0]
          int k5 = sIdx & 31;                    // k5&7 in {0,4}
          int sa = (k5 & 0x11) | ((k5 & 0x6) << 1) | ((k5 >> 2) & 0x2);
          size_t cb = (size_t)(bb * NH + hh) * (SEQ * DH)
                    + (size_t)(sIdx >> 5) * 2048 + (d >> 4) * 512
                    + (d & 15) * 8 + (size_t)(sa >> 3) * 128;
          *(unsigned int*)(out_vT + cb + (sa & 7))       = pk2bf(c[0] + bs, c[1] + bs);
          *(unsigned int*)(out_vT + cb + ((sa & 7) | 4)) = pk2bf(c[2] + bs, c[3] + bs);
        }
      } else {  // MODE_GELU: write swizzled fragment layout (out cols act as K next)
        float bs = bias0[n];
        int mtile = ((m0 + wm) >> 4) + mt;
        unsigned short* opb = out_bf + (size_t)(mtile * (N >> 5) + (n >> 5)) * 512
                              + quad * 4 * 32;
#pragma unroll
        for (int r = 0; r < 4; ++r) {
          float t = c[r] + bs;
          opb[r * 32 + ((n & 31) ^ ((r & 3) << 3))]
              = f2bf(0.5f * t * (1.0f + erff(t * 0.70710678118654752f)));
        }
      }
    }
}

// ---------------- GEMM 64x64, BK=128, LDS-staged from swizzled fragment layout ----------------
template <int TAG>
__global__ __launch_bounds__(256) void gemm64r(
    const unsigned short* __restrict__ A,   // swz fragment layout
    const unsigned short* __restrict__ Bt,  // swz fragment layout
    int M, int N, int K,
    const float* __restrict__ bias0,
    const float* __restrict__ resid,        // fp32 [M,N]
    float* __restrict__ out_f)              // fp32 [M,N]
{
  const int mb = M >> 6;
  int m0 = (blockIdx.x % mb) << 6;        // m-major ordering
  int n0 = (blockIdx.x / mb) << 6;
  int tid = threadIdx.x;
  int wave = tid >> 6, lane = tid & 63;
  int quad = lane >> 4, l16 = lane & 15;
  int wm = (wave & 1) << 5;
  int wn = (wave >> 1) << 5;
  int KT = K >> 5;
  const size_t TS = (size_t)KT * 512;
  int swq = (quad ^ (l16 & 3)) << 3;

  __shared__ __align__(16) unsigned short As[4][64 * 32];
  __shared__ __align__(16) unsigned short Bs[4][64 * 32];

  f32x4 acc[2][2];
#pragma unroll
  for (int i = 0; i < 2; ++i)
#pragma unroll
    for (int j = 0; j < 2; ++j) acc[i][j] = (f32x4){0.f, 0.f, 0.f, 0.f};

  // wave stages rows [wave*16, wave*16+16) = mtile wave
  const unsigned short* gA = A + (size_t)((m0 >> 4) + wave) * TS + lane * 8;
  const unsigned short* gB = Bt + (size_t)((n0 >> 4) + wave) * TS + lane * 8;
  unsigned short* lA = &As[0][wave * 512];
  unsigned short* lB = &Bs[0][wave * 512];
  const int CH = 64 * 32;   // chunk stride in shorts

  for (int ktb = 0; ktb < KT; ktb += 4) {
#pragma unroll
    for (int kc = 0; kc < 4; ++kc) {
      gld16(gA + (size_t)(ktb + kc) * 512, lA + kc * CH);
      gld16(gB + (size_t)(ktb + kc) * 512, lB + kc * CH);
    }
    __syncthreads();
#pragma unroll
    for (int kc = 0; kc < 4; ++kc) {
      short8 af[2], bfr[2];
#pragma unroll
      for (int t = 0; t < 2; ++t)
        af[t] = *(const short8*)(&As[kc][(wm + t * 16 + l16) * 32 + swq]);
#pragma unroll
      for (int t = 0; t < 2; ++t)
        bfr[t] = *(const short8*)(&Bs[kc][(wn + t * 16 + l16) * 32 + swq]);
#pragma unroll
      for (int i = 0; i < 2; ++i)
#pragma unroll
        for (int j = 0; j < 2; ++j)
          acc[i][j] = mfma16(af[i], bfr[j], acc[i][j]);
    }
    __syncthreads();
  }

#pragma unroll
  for (int mt = 0; mt < 2; ++mt)
#pragma unroll
    for (int nt = 0; nt < 2; ++nt) {
      f32x4 c = acc[mt][nt];
      int m = m0 + wm + mt * 16 + quad * 4;
      int n = n0 + wn + nt * 16 + l16;
      float bs = bias0[n];
      const float* rp = resid + (size_t)m * N + n;
      float* op = out_f + (size_t)m * N + n;
#pragma unroll
      for (int r = 0; r < 4; ++r) op[(size_t)r * N] = rp[(size_t)r * N] + c[r] + bs;
    }
}

// ---------------- flash attention v15: 8 waves/block, 256 keys/wave, sane VGPR bound ----------------
// v14 structure but __launch_bounds__(512,4): VGPR cap 128 (no spill); at the
// natural ~64 VGPR the HW still reaches 8 waves/SIMD -> 32 waves/CU.
__global__ __launch_bounds__(512, 4) void flash_attn_kernel(
    const unsigned short* __restrict__ q,   // [B,NH,S,DH]
    const unsigned short* __restrict__ k,   // K' layout
    const unsigned short* __restrict__ vT,  // V' layout (permuted)
    unsigned short* __restrict__ ctx)       // swz fragment layout [MTOK, 768]
{
  const float CEXP = 0.18033688011112042f;  // (1/8) * log2(e)
  int bh = blockIdx.x % 24;
  int qblk = blockIdx.x / 24;
  int b = bh / NH, h = bh % NH;
  int tid = threadIdx.x;
  int wave = tid >> 6, lane = tid & 63;
  int quad = lane >> 4, l16 = lane & 15;
  int qbase = qblk << 5;

  const unsigned short* qp = q + ((size_t)bh * SEQ + qbase) * DH;
  const unsigned short* kbh = k + (size_t)bh * (SEQ * DH);
  const unsigned short* vbh = vT + (size_t)bh * (SEQ * DH);

  short8 qf00 = *(const short8*)(qp + l16 * DH + quad * 8);
  short8 qf01 = *(const short8*)(qp + l16 * DH + 32 + quad * 8);
  short8 qf10 = *(const short8*)(qp + (16 + l16) * DH + quad * 8);
  short8 qf11 = *(const short8*)(qp + (16 + l16) * DH + 32 + quad * 8);

  // all-ones bf16 fragment (1.0 = 0x3F80)
  const short ONE = (short)0x3F80;
  short8 ones = (short8){ONE, ONE, ONE, ONE, ONE, ONE, ONE, ONE};

  f32x4 oacc[2][4];
  f32x4 lacc[2];
#pragma unroll
  for (int t = 0; t < 2; ++t) {
    lacc[t] = (f32x4){0.f, 0.f, 0.f, 0.f};
#pragma unroll
    for (int dt = 0; dt < 4; ++dt) oacc[t][dt] = (f32x4){0.f, 0.f, 0.f, 0.f};
  }

  int klin = (l16 * 4 + quad) * 8;
  int vlin = (quad * 16 + l16) * 8;

  int keylo = wave << 8;                      // 256 keys per wave
  for (int key0 = keylo; key0 < keylo + 256; key0 += 32) {
    int cbase = (key0 >> 5) * 2048;
    short8 ka0 = *(const short8*)(kbh + cbase + klin);
    short8 ka1 = *(const short8*)(kbh + cbase + 512 + klin);
    short8 kb0 = *(const short8*)(kbh + cbase + 1024 + klin);
    short8 kb1 = *(const short8*)(kbh + cbase + 1536 + klin);
    short8 vf0 = *(const short8*)(vbh + cbase + 0 * 512 + vlin);
    short8 vf1 = *(const short8*)(vbh + cbase + 1 * 512 + vlin);
    short8 vf2 = *(const short8*)(vbh + cbase + 2 * 512 + vlin);
    short8 vf3 = *(const short8*)(vbh + cbase + 3 * 512 + vlin);

#pragma unroll
    for (int t = 0; t < 2; ++t) {
      short8 q0 = t ? qf10 : qf00;
      short8 q1 = t ? qf11 : qf01;
      f32x4 s0 = (f32x4){0.f, 0.f, 0.f, 0.f};
      f32x4 s1 = (f32x4){0.f, 0.f, 0.f, 0.f};
      s0 = mfma16(ka0, q0, s0);
      s0 = mfma16(ka1, q1, s0);
      s1 = mfma16(kb0, q0, s1);
      s1 = mfma16(kb1, q1, s1);

      f32x4 p0, p1;
#pragma unroll
      for (int r = 0; r < 4; ++r) {
        p0[r] = __builtin_amdgcn_exp2f(s0[r] * CEXP);
        p1[r] = __builtin_amdgcn_exp2f(s1[r] * CEXP);
      }

      unsigned int d00 = pktrunc(p0[0], p0[1]);
      unsigned int d01 = pktrunc(p0[2], p0[3]);
      unsigned int d10 = pktrunc(p1[0], p1[1]);
      unsigned int d11 = pktrunc(p1[2], p1[3]);

      uint2v rA = __builtin_amdgcn_permlane32_swap(d00, d10, false, false);
      uint2v rB = __builtin_amdgcn_permlane32_swap(d01, d11, false, false);
      union { short8 s; unsigned int i[4]; } pf;
      pf.i[0] = rA[0];
      pf.i[1] = rA[1];
      pf.i[2] = rB[0];
      pf.i[3] = rB[1];

      oacc[t][0] = mfma16(vf0, pf.s, oacc[t][0]);
      oacc[t][1] = mfma16(vf1, pf.s, oacc[t][1]);
      oacc[t][2] = mfma16(vf2, pf.s, oacc[t][2]);
      oacc[t][3] = mfma16(vf3, pf.s, oacc[t][3]);
      lacc[t]    = mfma16(ones, pf.s, lacc[t]);   // L row-sum on matrix pipe
    }
  }

  __shared__ float lbuf[8][2][16];
  __shared__ uint2 obuf[8][2][4][64];

  // every accumulator row of lacc holds L for q=l16; take slot 0 from quad 0
  if (lane < 16) {
    lbuf[wave][0][lane] = lacc[0][0];
    lbuf[wave][1][lane] = lacc[1][0];
  }
#pragma unroll
  for (int t = 0; t < 2; ++t)
#pragma unroll
    for (int dt = 0; dt < 4; ++dt) {
      uint2 pk;
      pk.x = pk2bf(oacc[t][dt][0], oacc[t][dt][1]);
      pk.y = pk2bf(oacc[t][dt][2], oacc[t][dt][3]);
      obuf[wave][t][dt][lane] = pk;
    }
  __syncthreads();

  {
    int t = wave >> 2, dt = wave & 3;     // each wave reduces one (t,dt) combo
    f32x4 sum = (f32x4){0.f, 0.f, 0.f, 0.f};
#pragma unroll
    for (int w = 0; w < 8; ++w) {
      uint2 pk = obuf[w][t][dt][lane];
      sum[0] += bf2f((unsigned short)(pk.x & 0xffff));
      sum[1] += bf2f((unsigned short)(pk.x >> 16));
      sum[2] += bf2f((unsigned short)(pk.y & 0xffff));
      sum[3] += bf2f((unsigned short)(pk.y >> 16));
    }
    float lstar = 0.f;
#pragma unroll
    for (int w = 0; w < 8; ++w) lstar += lbuf[w][t][l16];
    float rinv = 1.0f / lstar;
    uint2 res;
    res.x = pk2bf(sum[0] * rinv, sum[1] * rinv);
    res.y = pk2bf(sum[2] * rinv, sum[3] * rinv);
    // swizzled fragment write: row r=l16, col c = (dt&1)*16 + quad*4, XOR bits 3-4
    int colsw = (((dt & 1) * 16 + quad * 4)) ^ ((l16 & 3) << 3);
    unsigned short* crow = ctx
        + ((size_t)((b * SEQ + qbase + t * 16) >> 4) * 24 + h * 2 + (dt >> 1)) * 512
        + l16 * 32 + colsw;
    *(uint2*)crow = res;
  }
}

// ---------------- launch ----------------
extern "C" void kernel_launch(void* const* d_in, const int* in_sizes, int n_in,
                              void* d_out, int out_size, void* d_ws, size_t ws_size,
                              hipStream_t stream) {
  const float* latent = (const float*)d_in[0];
  const float* ln1_w = (const float*)d_in[1];
  const float* ln1_b = (const float*)d_in[2];
  const float* Wq = (const float*)d_in[3];
  const float* bq = (const float*)d_in[4];
  const float* Wk = (const float*)d_in[5];
  const float* bk = (const float*)d_in[6];
  const float* Wv = (const float*)d_in[7];
  const float* bv = (const float*)d_in[8];
  const float* Wo = (const float*)d_in[9];
  const float* bo = (const float*)d_in[10];
  const float* ln2_w = (const float*)d_in[11];
  const float* ln2_b = (const float*)d_in[12];
  const float* W1 = (const float*)d_in[13];
  const float* b1 = (const float*)d_in[14];
  const float* W2 = (const float*)d_in[15];
  const float* b2 = (const float*)d_in[16];
  float* out = (float*)d_out;

  char* ws = (char*)d_ws;
  unsigned short* WqkvT = (unsigned short*)ws; ws += (size_t)2304 * 768 * 2;
  unsigned short* WoT   = (unsigned short*)ws; ws += (size_t)768 * 768 * 2;
  unsigned short* W1T   = (unsigned short*)ws; ws += (size_t)3072 * 768 * 2;
  unsigned short* W2T   = (unsigned short*)ws; ws += (size_t)768 * 3072 * 2;
  unsigned short* nx    = (unsigned short*)ws; ws += (size_t)MTOK * H * 2;
  unsigned short* nx2   = (unsigned short*)ws; ws += (size_t)MTOK * H * 2;
  unsigned short* qb    = (unsigned short*)ws; ws += (size_t)MTOK * H * 2;
  unsigned short* kb    = (unsigned short*)ws; ws += (size_t)MTOK * H * 2;
  unsigned short* vTb   = (unsigned short*)ws; ws += (size_t)MTOK * H * 2;
  unsigned short* ctx   = (unsigned short*)ws; ws += (size_t)MTOK * H * 2;
  unsigned short* hbuf  = (unsigned short*)ws; ws += (size_t)MTOK * FF * 2;
  float* x1             = (float*)ws;          ws += (size_t)MTOK * H * 4;

  // weight transposes (swz fragment layout) + LN1 (swz fragment layout), one launch
  prep_kernel<<<6912 + MTOK, 256, 0, stream>>>(
      Wq, Wk, Wv, Wo, W1, W2, WqkvT, WoT, W1T, W2T,
      latent, ln1_w, ln1_b, nx);

  // QKV projection (fused, N=2304), staged BK=64; K/V written in K'/V' layouts
  gemm128<MODE_QKV><<<32 * 18, 256, 0, stream>>>(
      nx, WqkvT, MTOK, 2304, 768, bq, bk, bv,
      qb, kb, vTb, nullptr);

  // attention (flash v15, 8 waves/block; ctx written in swz fragment layout)
  flash_attn_kernel<<<24 * 64, 512, 0, stream>>>(qb, kb, vTb, ctx);

  // output projection + residual -> x1 (fp32), staged BK=128
  gemm64r<0><<<64 * 12, 256, 0, stream>>>(
      ctx, WoT, MTOK, 768, 768, bo, latent, x1);

  // LN2 (swz fragment layout out)
  ln_kernel<<<MTOK, 256, 0, stream>>>(x1, ln2_w, ln2_b, nx2);

  // FFN up + GELU -> hbuf (swz fragment layout, K-dim 3072), staged BK=64
  gemm128<MODE_GELU><<<32 * 24, 256, 0, stream>>>(
      nx2, W1T, MTOK, 3072, 768, b1, nullptr, nullptr,
      nullptr, nullptr, nullptr, hbuf);

  // FFN down + residual -> d_out (fp32), staged BK=128
  gemm64r<1><<<64 * 12, 256, 0, stream>>>(
      hbuf, W2T, MTOK, 768, 3072, b2, x1, out);
}

// Round 16
// 255.125 us; speedup vs baseline: 2.1696x; 1.0205x over previous
//
#include <hip/hip_runtime.h>

#define H 768
#define FF 3072
#define NH 12
#define DH 64
#define SEQ 2048
#define MTOK 4096

typedef __attribute__((ext_vector_type(8))) short short8;
typedef __attribute__((ext_vector_type(4))) float f32x4;
typedef __attribute__((ext_vector_type(2))) unsigned int uint2v;

// swizzled fragment layout for all GEMM operands (A [M,K] and B^T [N,K] alike):
//   tile(mt,kt) base = ((m>>4)*(K>>5) + (k>>5))*512   [shorts], 16x32 tile
//   in-tile off(r=m&15, c=k&31) = r*32 + (c ^ ((r&3)<<3))     <- T2 XOR swizzle
// each tile = 1KB contiguous -> staged to LDS linearly by gld16; GEMM ds_read
// applies the same XOR.

__device__ __forceinline__ f32x4 mfma16(short8 a, short8 b, f32x4 c) {
  return __builtin_amdgcn_mfma_f32_16x16x32_bf16(a, b, c, 0, 0, 0);
}

__device__ __forceinline__ unsigned short f2bf(float f) {
  union { float f; unsigned int u; } c; c.f = f;
  unsigned int u = c.u;
  u += 0x7fffu + ((u >> 16) & 1u);  // round-to-nearest-even
  return (unsigned short)(u >> 16);
}
__device__ __forceinline__ float bf2f(unsigned short s) {
  union { unsigned int u; float f; } c; c.u = ((unsigned int)s) << 16;
  return c.f;
}
__device__ __forceinline__ unsigned int pk2bf(float lo, float hi) {
  return (unsigned int)f2bf(lo) | ((unsigned int)f2bf(hi) << 16);
}
// truncating bf16 pair pack: one v_perm_b32
__device__ __forceinline__ unsigned int pktrunc(float lo, float hi) {
  union { float f; unsigned int u; } a, b; a.f = hi; b.f = lo;
  return __builtin_amdgcn_perm(a.u, b.u, 0x07060302u);
}

// async global->LDS, 16B per lane; LDS dest = wave-uniform base + lane*16
__device__ __forceinline__ void gld16(const unsigned short* g, unsigned short* l) {
  __builtin_amdgcn_global_load_lds(
      (const __attribute__((address_space(1))) void*)g,
      (__attribute__((address_space(3))) void*)l, 16, 0, 0);
}

// wave-per-row LayerNorm body: row of 768 fp32 -> swizzled fragment bf16
__device__ __forceinline__ void ln_row(const float* __restrict__ xr, int row,
                                       const float* __restrict__ w,
                                       const float* __restrict__ b,
                                       unsigned short* __restrict__ out,
                                       int lane) {
  const float4* xv = (const float4*)xr;
  const float4* wv = (const float4*)w;
  const float4* bv = (const float4*)b;
  float4 v[3];
  float s = 0.f, ss = 0.f;
#pragma unroll
  for (int j = 0; j < 3; ++j) {
    v[j] = xv[lane + j * 64];
    s += v[j].x + v[j].y + v[j].z + v[j].w;
    ss += v[j].x * v[j].x + v[j].y * v[j].y + v[j].z * v[j].z + v[j].w * v[j].w;
  }
#pragma unroll
  for (int off = 32; off > 0; off >>= 1) {
    s += __shfl_xor(s, off);
    ss += __shfl_xor(ss, off);
  }
  float mu = s * (1.0f / H);
  float var = ss * (1.0f / H) - mu * mu;
  float rs = rsqrtf(var + 1e-6f);
  unsigned short* orow = out + (size_t)(row >> 4) * (24 * 512) + (row & 15) * 32;
#pragma unroll
  for (int j = 0; j < 3; ++j) {
    int c0 = lane * 4 + j * 256;
    float4 wj = wv[lane + j * 64];
    float4 bj = bv[lane + j * 64];
    float a0 = (v[j].x - mu) * rs * wj.x + bj.x;
    float a1 = (v[j].y - mu) * rs * wj.y + bj.y;
    float a2 = (v[j].z - mu) * rs * wj.z + bj.z;
    float a3 = (v[j].w - mu) * rs * wj.w + bj.w;
    int g = c0 >> 5;
    int swc = (c0 & 31) ^ ((row & 3) << 3);
    uint2 pk;
    pk.x = pk2bf(a0, a1);
    pk.y = pk2bf(a2, a3);
    *(uint2*)(orow + (size_t)g * 512 + swc) = pk;
  }
}

// ---------------- fused: weight transposes (bid<1728, 4 k-subtiles each) + LN1 ----------------
__global__ __launch_bounds__(256) void prep_kernel(
    const float* __restrict__ Wq, const float* __restrict__ Wk,
    const float* __restrict__ Wv, const float* __restrict__ Wo,
    const float* __restrict__ W1, const float* __restrict__ W2,
    unsigned short* __restrict__ WqkvT, unsigned short* __restrict__ WoT,
    unsigned short* __restrict__ W1T, unsigned short* __restrict__ W2T,
    const float* __restrict__ latent, const float* __restrict__ ln1_w,
    const float* __restrict__ ln1_b, unsigned short* __restrict__ nx) {
  int bid = blockIdx.x;
  int tid = threadIdx.x;
  if (bid >= 1728) {
    // LN1: 4 rows per block, one wave per row, no barriers
    int wave = tid >> 6, lane = tid & 63;
    int row = (bid - 1728) * 4 + wave;
    ln_row(latent + (size_t)row * H, row, ln1_w, ln1_b, nx, lane);
    return;
  }
  const float* in; unsigned short* out; int K, N, t0;
  if (bid < 432) {
    K = 768; N = 768;
    int sub = bid / 144; t0 = bid % 144;
    in = (sub == 0) ? Wq : (sub == 1) ? Wk : Wv;
    out = WqkvT + (size_t)sub * 768 * 768;
  } else if (bid < 576) { in = Wo; out = WoT; K = 768;  N = 768;  t0 = bid - 432; }
  else if (bid < 1152)  { in = W1; out = W1T; K = 768;  N = 3072; t0 = bid - 576; }
  else                  { in = W2; out = W2T; K = 3072; N = 768;  t0 = bid - 1152; }

  __shared__ float tile[2][32][33];
  int nb = N >> 5;
  int n0 = (t0 % nb) << 5;
  int kc0 = (t0 / nb) << 7;          // 128-wide k chunk, 4 subtiles of 32
  int tx = tid & 31, ty = tid >> 5;
  int KT5 = K >> 5;
#pragma unroll
  for (int kk = 0; kk < 4; ++kk) {
    int k0 = kc0 + kk * 32;
    int bsel = kk & 1;
#pragma unroll
    for (int yy = 0; yy < 4; ++yy)
      tile[bsel][ty + yy * 8][tx] = in[(size_t)(k0 + ty + yy * 8) * N + n0 + tx];
    __syncthreads();
#pragma unroll
    for (int yy = 0; yy < 4; ++yy) {
      int n = n0 + ty + yy * 8;
      out[(size_t)((n >> 4) * KT5 + (k0 >> 5)) * 512 + (n & 15) * 32
          + (tx ^ ((n & 3) << 3))]
          = f2bf(tile[bsel][tx][ty + yy * 8]);
    }
  }
}

// ---------------- LayerNorm fp32 [rows][768] -> bf16 swizzled fragment (4 rows/block) ----------------
__global__ __launch_bounds__(256) void ln_kernel(const float* __restrict__ x,
                                                 const float* __restrict__ w,
                                                 const float* __restrict__ b,
                                                 unsigned short* __restrict__ out) {
  int wave = threadIdx.x >> 6, lane = threadIdx.x & 63;
  int row = blockIdx.x * 4 + wave;
  ln_row(x + (size_t)row * H, row, w, b, out, lane);
}

// ---------------- GEMM 128x128, BK=64, LDS-staged from swizzled fragment layout ----------------
// staging = contiguous 1KB tile copies; ds_read applies the row XOR
// K' layout (per bh, per 32-key chunk c): shorts offset =
//   c*2048 + sub*1024 + dhh*512 + k16*32 + (dh&31)
// V' layout (per bh, per chunk c): c*2048 + dt*512 + (slot>>3)*128 + (d&15)*8 + (slot&7)
//   slot bits [k4 k2 k1 k3 k0] of key5 bits [k4 k3 k2 k1 k0]  (pi^-1 for permlane32_swap)
enum { MODE_QKV = 0, MODE_RESID = 1, MODE_GELU = 2 };

template <int MODE>
__global__ __launch_bounds__(256) void gemm128(
    const unsigned short* __restrict__ A,   // swz fragment layout, M rows, K cols
    const unsigned short* __restrict__ Bt,  // swz fragment layout, N rows, K cols
    int M, int N, int K,
    const float* __restrict__ bias0,
    const float* __restrict__ bias1,
    const float* __restrict__ bias2,
    unsigned short* __restrict__ out_q,
    unsigned short* __restrict__ out_k,    // K' layout
    unsigned short* __restrict__ out_vT,   // V' layout (permuted)
    unsigned short* __restrict__ out_bf)   // swz fragment layout [M, N-as-K]
{
  const int mb = M >> 7;
  int m0 = (blockIdx.x % mb) << 7;        // m-major: same n-strip stays adjacent
  int n0 = (blockIdx.x / mb) << 7;
  int tid = threadIdx.x;
  int wave = tid >> 6, lane = tid & 63;
  int quad = lane >> 4, l16 = lane & 15;
  int wm = (wave & 1) << 6;
  int wn = (wave >> 1) << 6;
  int KT = K >> 5;
  const size_t TS = (size_t)KT * 512;     // shorts per 16-row tile strip
  int swq = (quad ^ (l16 & 3)) << 3;      // swizzled in-tile column (shorts)

  __shared__ __align__(16) unsigned short As[2][128 * 32];
  __shared__ __align__(16) unsigned short Bs[2][128 * 32];

  f32x4 acc[4][4];
#pragma unroll
  for (int i = 0; i < 4; ++i)
#pragma unroll
    for (int j = 0; j < 4; ++j) acc[i][j] = (f32x4){0.f, 0.f, 0.f, 0.f};

  // wave stages rows [wave*32, wave*32+32) = mtiles 2*wave, 2*wave+1
  const unsigned short* gA = A + (size_t)((m0 >> 4) + wave * 2) * TS + lane * 8;
  const unsigned short* gB = Bt + (size_t)((n0 >> 4) + wave * 2) * TS + lane * 8;
  unsigned short* lA0 = &As[0][(wave * 32) * 32];
  unsigned short* lA1 = &As[0][(wave * 32 + 16) * 32];
  unsigned short* lB0 = &Bs[0][(wave * 32) * 32];
  unsigned short* lB1 = &Bs[0][(wave * 32 + 16) * 32];
  const int CH = 128 * 32;   // chunk stride in shorts

  for (int ktb = 0; ktb < KT; ktb += 2) {
#pragma unroll
    for (int kc = 0; kc < 2; ++kc) {
      gld16(gA + (size_t)(ktb + kc) * 512,      lA0 + kc * CH);
      gld16(gA + TS + (size_t)(ktb + kc) * 512, lA1 + kc * CH);
      gld16(gB + (size_t)(ktb + kc) * 512,      lB0 + kc * CH);
      gld16(gB + TS + (size_t)(ktb + kc) * 512, lB1 + kc * CH);
    }
    __syncthreads();
#pragma unroll
    for (int kc = 0; kc < 2; ++kc) {
      short8 af[4], bfr[4];
#pragma unroll
      for (int t = 0; t < 4; ++t)
        af[t] = *(const short8*)(&As[kc][(wm + t * 16 + l16) * 32 + swq]);
#pragma unroll
      for (int t = 0; t < 4; ++t)
        bfr[t] = *(const short8*)(&Bs[kc][(wn + t * 16 + l16) * 32 + swq]);
#pragma unroll
      for (int i = 0; i < 4; ++i)
#pragma unroll
        for (int j = 0; j < 4; ++j)
          acc[i][j] = mfma16(af[i], bfr[j], acc[i][j]);
    }
    __syncthreads();
  }

#pragma unroll
  for (int mt = 0; mt < 4; ++mt)
#pragma unroll
    for (int nt = 0; nt < 4; ++nt) {
      f32x4 c = acc[mt][nt];
      int m = m0 + wm + mt * 16 + quad * 4;
      int n = n0 + wn + nt * 16 + l16;
      if (MODE == MODE_QKV) {
        int bb = m >> 11, sIdx = m & 2047;
        if (n < 768) {
          float bs = bias0[n];
          int hh = n >> 6, d = n & 63;
          unsigned short* dst = out_q + (((size_t)(bb * NH + hh)) * SEQ + sIdx) * DH + d;
#pragma unroll
          for (int r = 0; r < 4; ++r) dst[r * DH] = f2bf(c[r] + bs);
        } else if (n < 1536) {
          int nn = n - 768;
          float bs = bias1[nn];
          int hh = nn >> 6, d = nn & 63;
          size_t base = (size_t)(bb * NH + hh) * (SEQ * DH)
                      + (size_t)(sIdx >> 5) * 2048 + ((sIdx >> 4) & 1) * 1024
                      + (d >> 5) * 512 + (sIdx & 15) * 32 + (d & 31);
#pragma unroll
          for (int r = 0; r < 4; ++r) out_k[base + r * 32] = f2bf(c[r] + bs);
        } else {
          int nn = n - 1536;
          float bs = bias2[nn];
          int hh = nn >> 6, d = nn & 63;
          // permuted V' slot: key5 bits [k4 k3 k2 k1 k0] -> slot [k4 k2 k1 k3 k0]
          int k5 = sIdx & 31;                    // k5&7 in {0,4}
          int sa = (k5 & 0x11) | ((k5 & 0x6) << 1) | ((k5 >> 2) & 0x2);
          size_t cb = (size_t)(bb * NH + hh) * (SEQ * DH)
                    + (size_t)(sIdx >> 5) * 2048 + (d >> 4) * 512
                    + (d & 15) * 8 + (size_t)(sa >> 3) * 128;
          *(unsigned int*)(out_vT + cb + (sa & 7))       = pk2bf(c[0] + bs, c[1] + bs);
          *(unsigned int*)(out_vT + cb + ((sa & 7) | 4)) = pk2bf(c[2] + bs, c[3] + bs);
        }
      } else {  // MODE_GELU: write swizzled fragment layout (out cols act as K next)
        float bs = bias0[n];
        int mtile = ((m0 + wm) >> 4) + mt;
        unsigned short* opb = out_bf + (size_t)(mtile * (N >> 5) + (n >> 5)) * 512
                              + quad * 4 * 32;
#pragma unroll
        for (int r = 0; r < 4; ++r) {
          float t = c[r] + bs;
          opb[r * 32 + ((n & 31) ^ ((r & 3) << 3))]
              = f2bf(0.5f * t * (1.0f + erff(t * 0.70710678118654752f)));
        }
      }
    }
}

// ---------------- GEMM 64x64, BK=128, LDS-staged from swizzled fragment layout ----------------
template <int TAG>
__global__ __launch_bounds__(256) void gemm64r(
    const unsigned short* __restrict__ A,   // swz fragment layout
    const unsigned short* __restrict__ Bt,  // swz fragment layout
    int M, int N, int K,
    const float* __restrict__ bias0,
    const float* __restrict__ resid,        // fp32 [M,N]
    float* __restrict__ out_f)              // fp32 [M,N]
{
  const int mb = M >> 6;
  int m0 = (blockIdx.x % mb) << 6;        // m-major ordering
  int n0 = (blockIdx.x / mb) << 6;
  int tid = threadIdx.x;
  int wave = tid >> 6, lane = tid & 63;
  int quad = lane >> 4, l16 = lane & 15;
  int wm = (wave & 1) << 5;
  int wn = (wave >> 1) << 5;
  int KT = K >> 5;
  const size_t TS = (size_t)KT * 512;
  int swq = (quad ^ (l16 & 3)) << 3;

  __shared__ __align__(16) unsigned short As[4][64 * 32];
  __shared__ __align__(16) unsigned short Bs[4][64 * 32];

  f32x4 acc[2][2];
#pragma unroll
  for (int i = 0; i < 2; ++i)
#pragma unroll
    for (int j = 0; j < 2; ++j) acc[i][j] = (f32x4){0.f, 0.f, 0.f, 0.f};

  // wave stages rows [wave*16, wave*16+16) = mtile wave
  const unsigned short* gA = A + (size_t)((m0 >> 4) + wave) * TS + lane * 8;
  const unsigned short* gB = Bt + (size_t)((n0 >> 4) + wave) * TS + lane * 8;
  unsigned short* lA = &As[0][wave * 512];
  unsigned short* lB = &Bs[0][wave * 512];
  const int CH = 64 * 32;   // chunk stride in shorts

  for (int ktb = 0; ktb < KT; ktb += 4) {
#pragma unroll
    for (int kc = 0; kc < 4; ++kc) {
      gld16(gA + (size_t)(ktb + kc) * 512, lA + kc * CH);
      gld16(gB + (size_t)(ktb + kc) * 512, lB + kc * CH);
    }
    __syncthreads();
#pragma unroll
    for (int kc = 0; kc < 4; ++kc) {
      short8 af[2], bfr[2];
#pragma unroll
      for (int t = 0; t < 2; ++t)
        af[t] = *(const short8*)(&As[kc][(wm + t * 16 + l16) * 32 + swq]);
#pragma unroll
      for (int t = 0; t < 2; ++t)
        bfr[t] = *(const short8*)(&Bs[kc][(wn + t * 16 + l16) * 32 + swq]);
#pragma unroll
      for (int i = 0; i < 2; ++i)
#pragma unroll
        for (int j = 0; j < 2; ++j)
          acc[i][j] = mfma16(af[i], bfr[j], acc[i][j]);
    }
    __syncthreads();
  }

#pragma unroll
  for (int mt = 0; mt < 2; ++mt)
#pragma unroll
    for (int nt = 0; nt < 2; ++nt) {
      f32x4 c = acc[mt][nt];
      int m = m0 + wm + mt * 16 + quad * 4;
      int n = n0 + wn + nt * 16 + l16;
      float bs = bias0[n];
      const float* rp = resid + (size_t)m * N + n;
      float* op = out_f + (size_t)m * N + n;
#pragma unroll
      for (int r = 0; r < 4; ++r) op[(size_t)r * N] = rp[(size_t)r * N] + c[r] + bs;
    }
}

// ---------------- flash attention v13: 4 waves, permlane + L-via-MFMA ----------------
__global__ __launch_bounds__(256, 4) void flash_attn_kernel(
    const unsigned short* __restrict__ q,   // [B,NH,S,DH]
    const unsigned short* __restrict__ k,   // K' layout
    const unsigned short* __restrict__ vT,  // V' layout (permuted)
    unsigned short* __restrict__ ctx)       // swz fragment layout [MTOK, 768]
{
  const float CEXP = 0.18033688011112042f;  // (1/8) * log2(e)
  int bh = blockIdx.x % 24;
  int qblk = blockIdx.x / 24;
  int b = bh / NH, h = bh % NH;
  int tid = threadIdx.x;
  int wave = tid >> 6, lane = tid & 63;
  int quad = lane >> 4, l16 = lane & 15;
  int qbase = qblk << 5;

  const unsigned short* qp = q + ((size_t)bh * SEQ + qbase) * DH;
  const unsigned short* kbh = k + (size_t)bh * (SEQ * DH);
  const unsigned short* vbh = vT + (size_t)bh * (SEQ * DH);

  short8 qf00 = *(const short8*)(qp + l16 * DH + quad * 8);
  short8 qf01 = *(const short8*)(qp + l16 * DH + 32 + quad * 8);
  short8 qf10 = *(const short8*)(qp + (16 + l16) * DH + quad * 8);
  short8 qf11 = *(const short8*)(qp + (16 + l16) * DH + 32 + quad * 8);

  // all-ones bf16 fragment (1.0 = 0x3F80)
  const short ONE = (short)0x3F80;
  short8 ones = (short8){ONE, ONE, ONE, ONE, ONE, ONE, ONE, ONE};

  f32x4 oacc[2][4];
  f32x4 lacc[2];
#pragma unroll
  for (int t = 0; t < 2; ++t) {
    lacc[t] = (f32x4){0.f, 0.f, 0.f, 0.f};
#pragma unroll
    for (int dt = 0; dt < 4; ++dt) oacc[t][dt] = (f32x4){0.f, 0.f, 0.f, 0.f};
  }

  int klin = (l16 * 4 + quad) * 8;
  int vlin = (quad * 16 + l16) * 8;

  int keylo = wave << 9;
  for (int key0 = keylo; key0 < keylo + 512; key0 += 32) {
    int cbase = (key0 >> 5) * 2048;
    short8 ka0 = *(const short8*)(kbh + cbase + klin);
    short8 ka1 = *(const short8*)(kbh + cbase + 512 + klin);
    short8 kb0 = *(const short8*)(kbh + cbase + 1024 + klin);
    short8 kb1 = *(const short8*)(kbh + cbase + 1536 + klin);
    short8 vf0 = *(const short8*)(vbh + cbase + 0 * 512 + vlin);
    short8 vf1 = *(const short8*)(vbh + cbase + 1 * 512 + vlin);
    short8 vf2 = *(const short8*)(vbh + cbase + 2 * 512 + vlin);
    short8 vf3 = *(const short8*)(vbh + cbase + 3 * 512 + vlin);

#pragma unroll
    for (int t = 0; t < 2; ++t) {
      short8 q0 = t ? qf10 : qf00;
      short8 q1 = t ? qf11 : qf01;
      f32x4 s0 = (f32x4){0.f, 0.f, 0.f, 0.f};
      f32x4 s1 = (f32x4){0.f, 0.f, 0.f, 0.f};
      s0 = mfma16(ka0, q0, s0);
      s0 = mfma16(ka1, q1, s0);
      s1 = mfma16(kb0, q0, s1);
      s1 = mfma16(kb1, q1, s1);

      f32x4 p0, p1;
#pragma unroll
      for (int r = 0; r < 4; ++r) {
        p0[r] = __builtin_amdgcn_exp2f(s0[r] * CEXP);
        p1[r] = __builtin_amdgcn_exp2f(s1[r] * CEXP);
      }

      unsigned int d00 = pktrunc(p0[0], p0[1]);
      unsigned int d01 = pktrunc(p0[2], p0[3]);
      unsigned int d10 = pktrunc(p1[0], p1[1]);
      unsigned int d11 = pktrunc(p1[2], p1[3]);

      uint2v rA = __builtin_amdgcn_permlane32_swap(d00, d10, false, false);
      uint2v rB = __builtin_amdgcn_permlane32_swap(d01, d11, false, false);
      union { short8 s; unsigned int i[4]; } pf;
      pf.i[0] = rA[0];
      pf.i[1] = rA[1];
      pf.i[2] = rB[0];
      pf.i[3] = rB[1];

      oacc[t][0] = mfma16(vf0, pf.s, oacc[t][0]);
      oacc[t][1] = mfma16(vf1, pf.s, oacc[t][1]);
      oacc[t][2] = mfma16(vf2, pf.s, oacc[t][2]);
      oacc[t][3] = mfma16(vf3, pf.s, oacc[t][3]);
      lacc[t]    = mfma16(ones, pf.s, lacc[t]);   // L row-sum on matrix pipe
    }
  }

  __shared__ float lbuf[4][2][16];
  __shared__ uint2 obuf[4][2][4][64];

  // every accumulator row of lacc holds L for q=l16; take slot 0 from quad 0
  if (lane < 16) {
    lbuf[wave][0][lane] = lacc[0][0];
    lbuf[wave][1][lane] = lacc[1][0];
  }
#pragma unroll
  for (int t = 0; t < 2; ++t)
#pragma unroll
    for (int dt = 0; dt < 4; ++dt) {
      uint2 pk;
      pk.x = pk2bf(oacc[t][dt][0], oacc[t][dt][1]);
      pk.y = pk2bf(oacc[t][dt][2], oacc[t][dt][3]);
      obuf[wave][t][dt][lane] = pk;
    }
  __syncthreads();

#pragma unroll
  for (int pp = 0; pp < 2; ++pp) {
    int pi = wave * 2 + pp;
    int t = pi >> 2, dt = pi & 3;
    f32x4 sum = (f32x4){0.f, 0.f, 0.f, 0.f};
#pragma unroll
    for (int w = 0; w < 4; ++w) {
      uint2 pk = obuf[w][t][dt][lane];
      sum[0] += bf2f((unsigned short)(pk.x & 0xffff));
      sum[1] += bf2f((unsigned short)(pk.x >> 16));
      sum[2] += bf2f((unsigned short)(pk.y & 0xffff));
      sum[3] += bf2f((unsigned short)(pk.y >> 16));
    }
    float lstar = lbuf[0][t][l16] + lbuf[1][t][l16] + lbuf[2][t][l16] + lbuf[3][t][l16];
    float rinv = 1.0f / lstar;
    uint2 res;
    res.x = pk2bf(sum[0] * rinv, sum[1] * rinv);
    res.y = pk2bf(sum[2] * rinv, sum[3] * rinv);
    // swizzled fragment write: row r=l16, col c = (dt&1)*16 + quad*4, XOR bits 3-4
    int colsw = (((dt & 1) * 16 + quad * 4)) ^ ((l16 & 3) << 3);
    unsigned short* crow = ctx
        + ((size_t)((b * SEQ + qbase + t * 16) >> 4) * 24 + h * 2 + (dt >> 1)) * 512
        + l16 * 32 + colsw;
    *(uint2*)crow = res;
  }
}

// ---------------- launch ----------------
extern "C" void kernel_launch(void* const* d_in, const int* in_sizes, int n_in,
                              void* d_out, int out_size, void* d_ws, size_t ws_size,
                              hipStream_t stream) {
  const float* latent = (const float*)d_in[0];
  const float* ln1_w = (const float*)d_in[1];
  const float* ln1_b = (const float*)d_in[2];
  const float* Wq = (const float*)d_in[3];
  const float* bq = (const float*)d_in[4];
  const float* Wk = (const float*)d_in[5];
  const float* bk = (const float*)d_in[6];
  const float* Wv = (const float*)d_in[7];
  const float* bv = (const float*)d_in[8];
  const float* Wo = (const float*)d_in[9];
  const float* bo = (const float*)d_in[10];
  const float* ln2_w = (const float*)d_in[11];
  const float* ln2_b = (const float*)d_in[12];
  const float* W1 = (const float*)d_in[13];
  const float* b1 = (const float*)d_in[14];
  const float* W2 = (const float*)d_in[15];
  const float* b2 = (const float*)d_in[16];
  float* out = (float*)d_out;

  char* ws = (char*)d_ws;
  unsigned short* WqkvT = (unsigned short*)ws; ws += (size_t)2304 * 768 * 2;
  unsigned short* WoT   = (unsigned short*)ws; ws += (size_t)768 * 768 * 2;
  unsigned short* W1T   = (unsigned short*)ws; ws += (size_t)3072 * 768 * 2;
  unsigned short* W2T   = (unsigned short*)ws; ws += (size_t)768 * 3072 * 2;
  unsigned short* nx    = (unsigned short*)ws; ws += (size_t)MTOK * H * 2;
  unsigned short* nx2   = (unsigned short*)ws; ws += (size_t)MTOK * H * 2;
  unsigned short* qb    = (unsigned short*)ws; ws += (size_t)MTOK * H * 2;
  unsigned short* kb    = (unsigned short*)ws; ws += (size_t)MTOK * H * 2;
  unsigned short* vTb   = (unsigned short*)ws; ws += (size_t)MTOK * H * 2;
  unsigned short* ctx   = (unsigned short*)ws; ws += (size_t)MTOK * H * 2;
  unsigned short* hbuf  = (unsigned short*)ws; ws += (size_t)MTOK * FF * 2;
  float* x1             = (float*)ws;          ws += (size_t)MTOK * H * 4;

  // weight transposes (4 subtiles/block) + LN1 (wave-per-row), one launch
  prep_kernel<<<1728 + MTOK / 4, 256, 0, stream>>>(
      Wq, Wk, Wv, Wo, W1, W2, WqkvT, WoT, W1T, W2T,
      latent, ln1_w, ln1_b, nx);

  // QKV projection (fused, N=2304), staged BK=64; K/V written in K'/V' layouts
  gemm128<MODE_QKV><<<32 * 18, 256, 0, stream>>>(
      nx, WqkvT, MTOK, 2304, 768, bq, bk, bv,
      qb, kb, vTb, nullptr);

  // attention (flash v13; ctx written in swz fragment layout)
  flash_attn_kernel<<<24 * 64, 256, 0, stream>>>(qb, kb, vTb, ctx);

  // output projection + residual -> x1 (fp32), staged BK=128
  gemm64r<0><<<64 * 12, 256, 0, stream>>>(
      ctx, WoT, MTOK, 768, 768, bo, latent, x1);

  // LN2 (wave-per-row, swz fragment layout out)
  ln_kernel<<<MTOK / 4, 256, 0, stream>>>(x1, ln2_w, ln2_b, nx2);

  // FFN up + GELU -> hbuf (swz fragment layout, K-dim 3072), staged BK=64
  gemm128<MODE_GELU><<<32 * 24, 256, 0, stream>>>(
      nx2, W1T, MTOK, 3072, 768, b1, nullptr, nullptr,
      nullptr, nullptr, nullptr, hbuf);

  // FFN down + residual -> d_out (fp32), staged BK=128
  gemm64r<1><<<64 * 12, 256, 0, stream>>>(
      hbuf, W2T, MTOK, 768, 3072, b2, x1, out);
}